// Round 1
// baseline (43.551 us; speedup 1.0000x reference)
//
#include <hip/hip_runtime.h>
#include <math.h>

// ---------------------------------------------------------------------------
// HierarchicalCubeMap: mip pyramid build + per-ray trilinear cubemap sampling
// Inputs (f32): viewdirs (B,3), saSample (B,1), bg_mat (6,512,512,3),
//               brightness (1), mul (1), mipbias (1)
// Output (f32): (B,3) = clip(exp(clip(brightness,-1,2) + mul*sample), .01, 1000)
// ---------------------------------------------------------------------------

#define BASE_R 512
#define N_MIPS 10  // log2(512)+1

// 2x2 mean downsample: dst is (6, r, r, 3), src is (6, 2r, 2r, 3)
__global__ void downsample_kernel(const float* __restrict__ src,
                                  float* __restrict__ dst, int r, int n) {
    int idx = blockIdx.x * blockDim.x + threadIdx.x;
    if (idx >= n) return;
    int c = idx % 3;
    int t = idx / 3;
    int x = t % r;
    int y = (t / r) % r;
    int f = t / (r * r);
    int R2 = r * 2;
    const float* base = src + ((size_t)((f * R2 + 2 * y)) * R2 + 2 * x) * 3 + c;
    float a = base[0];
    float b = base[3];
    float cc = base[(size_t)R2 * 3];
    float d = base[(size_t)R2 * 3 + 3];
    dst[idx] = (a + b + cc + d) * 0.25f;
}

// pointer to mip level m: m==0 -> bg_mat, else offset into workspace pyramid
__device__ __forceinline__ const float* mip_base(const float* __restrict__ bg,
                                                 const float* __restrict__ ws,
                                                 int m) {
    if (m == 0) return bg;
    // offset(m) = sum_{k=1}^{m-1} 6*3*(512>>k)^2 = 6*(4^9 - 4^(10-m))
    return ws + (size_t)6 * (262144u - (1u << (2 * (10 - m))));
}

__device__ __forceinline__ void sample_mip(const float* __restrict__ tex, int Rm,
                                           int face, float s, float t,
                                           float out3[3]) {
    float u = s * (float)Rm - 0.5f;
    float v = t * (float)Rm - 0.5f;
    float u0 = floorf(u);
    float v0 = floorf(v);
    float fu = u - u0;
    float fv = v - v0;
    int u0i = min(max((int)u0, 0), Rm - 1);
    int u1i = min(max((int)u0 + 1, 0), Rm - 1);
    int v0i = min(max((int)v0, 0), Rm - 1);
    int v1i = min(max((int)v0 + 1, 0), Rm - 1);
    const float* r0 = tex + ((size_t)(face * Rm + v0i) * Rm) * 3;
    const float* r1 = tex + ((size_t)(face * Rm + v1i) * Rm) * 3;
    const float* p00 = r0 + (size_t)u0i * 3;
    const float* p01 = r0 + (size_t)u1i * 3;
    const float* p10 = r1 + (size_t)u0i * 3;
    const float* p11 = r1 + (size_t)u1i * 3;
#pragma unroll
    for (int c = 0; c < 3; ++c) {
        float top = p00[c] * (1.0f - fu) + p01[c] * fu;
        float bot = p10[c] * (1.0f - fu) + p11[c] * fu;
        out3[c] = top * (1.0f - fv) + bot * fv;
    }
}

__global__ void cubemap_sample_kernel(const float* __restrict__ vd,
                                      const float* __restrict__ sa,
                                      const float* __restrict__ bg,
                                      const float* __restrict__ ws,
                                      float* __restrict__ out, int B,
                                      const float* __restrict__ p_brightness,
                                      const float* __restrict__ p_mul,
                                      const float* __restrict__ p_mipbias) {
    int i = blockIdx.x * blockDim.x + threadIdx.x;
    if (i >= B) return;

    float x = vd[3 * i + 0];
    float y = vd[3 * i + 1];
    float z = vd[3 * i + 2];
    float ax = fabsf(x), ay = fabsf(y), az = fabsf(z);
    float ma = fmaxf(ax, fmaxf(ay, az));

    int face;
    float sc, tc;
    if (ax >= ay && ax >= az) {
        face = (x > 0.0f) ? 0 : 1;
        sc = (x > 0.0f) ? -z : z;
        tc = -y;
    } else if (ay >= az) {
        face = (y > 0.0f) ? 2 : 3;
        sc = x;
        tc = (y > 0.0f) ? z : -z;
    } else {
        face = (z > 0.0f) ? 4 : 5;
        sc = (z > 0.0f) ? x : -x;
        tc = -y;
    }
    float s = 0.5f * (sc / ma + 1.0f);
    float t = 0.5f * (tc / ma + 1.0f);

    // mip level: (saSample - log(clip(saTexel, EPS))) / log(4) / 2 + mipbias
    float distortion = 1.0f / ma;                         // 1 / ainf
    float saTexel = distortion * (1.0f / 262144.0f);      // /512/512 (exact pow2)
    const float EPSF = 1.1920928955078125e-07f;           // np.finfo(f32).eps
    const float LOG4 = 1.3862943611198906f;               // rounds to f32
    float mip = (sa[i] - logf(fmaxf(saTexel, EPSF))) / LOG4 * 0.5f + p_mipbias[0];
    mip = fminf(fmaxf(mip, 0.0f), (float)(N_MIPS - 1));

    int m0 = (int)floorf(mip);
    int m1 = min(m0 + 1, N_MIPS - 1);
    float frac = mip - (float)m0;

    float lo[3], hi[3];
    sample_mip(mip_base(bg, ws, m0), BASE_R >> m0, face, s, t, lo);
    sample_mip(mip_base(bg, ws, m1), BASE_R >> m1, face, s, t, hi);

    float bb = fminf(fmaxf(p_brightness[0], -1.0f), 2.0f);
    float mulv = p_mul[0];
#pragma unroll
    for (int c = 0; c < 3; ++c) {
        float xv = bb + mulv * (lo[c] * (1.0f - frac) + hi[c] * frac);
        float e = expf(xv);
        out[3 * i + c] = fminf(fmaxf(e, 0.01f), 1000.0f);
    }
}

extern "C" void kernel_launch(void* const* d_in, const int* in_sizes, int n_in,
                              void* d_out, int out_size, void* d_ws, size_t ws_size,
                              hipStream_t stream) {
    const float* viewdirs = (const float*)d_in[0];
    const float* saSample = (const float*)d_in[1];
    const float* bg_mat = (const float*)d_in[2];
    const float* brightness = (const float*)d_in[3];
    const float* mul = (const float*)d_in[4];
    const float* mipbias = (const float*)d_in[5];
    float* out = (float*)d_out;
    float* ws = (float*)d_ws;

    int B = in_sizes[1];  // saSample has B elements

    // Build mip pyramid: levels 1..9 stored contiguously in workspace.
    const float* src = bg_mat;
    size_t off = 0;
    for (int k = 1; k < N_MIPS; ++k) {
        int r = BASE_R >> k;
        int n = 6 * r * r * 3;
        int blocks = (n + 255) / 256;
        downsample_kernel<<<blocks, 256, 0, stream>>>(src, ws + off, r, n);
        src = ws + off;
        off += (size_t)n;
    }

    int blocks = (B + 255) / 256;
    cubemap_sample_kernel<<<blocks, 256, 0, stream>>>(
        viewdirs, saSample, bg_mat, ws, out, B, brightness, mul, mipbias);
}

// Round 2
// 33.878 us; speedup vs baseline: 1.2855x; 1.2855x over previous
//
#include <hip/hip_runtime.h>
#include <math.h>

// ---------------------------------------------------------------------------
// HierarchicalCubeMap: mip pyramid build (2 kernels) + per-ray trilinear
// cubemap sampling (1 kernel).
// Inputs (f32): viewdirs (B,3), saSample (B,1), bg_mat (6,512,512,3),
//               brightness (1), mul (1), mipbias (1)
// Output (f32): (B,3) = clip(exp(clip(brightness,-1,2) + mul*sample), .01, 1000)
// ---------------------------------------------------------------------------

#define BASE_R 512
#define N_MIPS 10  // log2(512)+1

// float offset of mip level m (m>=1) inside workspace pyramid:
// off(m) = sum_{k=1}^{m-1} 6*3*(512>>k)^2 = 6*(4^9 - 4^(10-m))
__device__ __host__ __forceinline__ size_t mip_off(int m) {
    return (size_t)6 * (262144u - (1u << (2 * (10 - m))));
}

// ---------------------------------------------------------------------------
// Fused pyramid: levels 1..6. Grid = 6 faces * 8*8 tiles of 64x64 texels.
// Each block: load 64x64x3 tile into LDS, reduce 6x, write each level out.
// Summation order matches the chained 2x2 downsample: (a+b+c+d)*0.25 with
// a=(2y,2x) b=(2y,2x+1) c=(2y+1,2x) d=(2y+1,2x+1).
// ---------------------------------------------------------------------------
__global__ __launch_bounds__(256) void pyramid_fused_kernel(
    const float* __restrict__ bg, float* __restrict__ ws) {
    __shared__ float bufA[64 * 64 * 3];  // 49152 B
    __shared__ float bufB[32 * 32 * 3];  // 12288 B

    const int tid = threadIdx.x;
    const int blk = blockIdx.x;
    const int tileX = blk & 7;
    const int tileY = (blk >> 3) & 7;
    const int f = blk >> 6;

    // Load 64 rows x 192 contiguous floats (=48 float4) per row.
    const size_t faceBase = (size_t)f * (512 * 512 * 3);
    for (int i = tid; i < 64 * 48; i += 256) {
        int row = i / 48;
        int col4 = i % 48;
        const float4 v = *reinterpret_cast<const float4*>(
            bg + faceBase + (size_t)(tileY * 64 + row) * 1536 + tileX * 192 + col4 * 4);
        *reinterpret_cast<float4*>(&bufA[row * 192 + col4 * 4]) = v;
    }
    __syncthreads();

    float* src = bufA;
    float* dst = bufB;
    int rs = 64;  // source tile dim
#pragma unroll
    for (int L = 1; L <= 6; ++L) {
        const int rd = rs >> 1;            // dest tile dim
        const int r = BASE_R >> L;         // dest level resolution
        float* gl = ws + mip_off(L) + (size_t)f * r * r * 3;
        const int y0 = tileY * rd;
        const int x0 = tileX * rd;
        const int n = rd * rd * 3;
        for (int i = tid; i < n; i += 256) {
            int c = i % 3;
            int t = i / 3;
            int x = t % rd;
            int y = t / rd;
            const float* p0 = src + ((2 * y) * rs + 2 * x) * 3 + c;
            const float* p1 = p0 + rs * 3;
            float m = (p0[0] + p0[3] + p1[0] + p1[3]) * 0.25f;
            dst[i] = m;
            gl[((size_t)(y0 + y) * r + (x0 + x)) * 3 + c] = m;
        }
        __syncthreads();
        float* tmp = src; src = dst; dst = tmp;
        rs = rd;
    }
}

// ---------------------------------------------------------------------------
// Tail: levels 7..9 from level 6 (6x8x8x3 = 1152 floats). One block.
// ---------------------------------------------------------------------------
__global__ __launch_bounds__(256) void pyramid_tail_kernel(float* __restrict__ ws) {
    __shared__ float l6[1152];
    __shared__ float l7[288];
    __shared__ float l8[72];
    const int tid = threadIdx.x;

    const float* g6 = ws + mip_off(6);
    for (int i = tid; i < 1152; i += 256) l6[i] = g6[i];
    __syncthreads();

    float* g7 = ws + mip_off(7);
    for (int i = tid; i < 288; i += 256) {
        int c = i % 3, t = i / 3;
        int x = t % 4, y = (t / 4) % 4, f = t / 16;
        const float* p0 = l6 + ((f * 8 + 2 * y) * 8 + 2 * x) * 3 + c;
        const float* p1 = p0 + 24;
        float m = (p0[0] + p0[3] + p1[0] + p1[3]) * 0.25f;
        l7[i] = m;
        g7[i] = m;
    }
    __syncthreads();

    float* g8 = ws + mip_off(8);
    for (int i = tid; i < 72; i += 256) {
        int c = i % 3, t = i / 3;
        int x = t % 2, y = (t / 2) % 2, f = t / 4;
        const float* p0 = l7 + ((f * 4 + 2 * y) * 4 + 2 * x) * 3 + c;
        const float* p1 = p0 + 12;
        float m = (p0[0] + p0[3] + p1[0] + p1[3]) * 0.25f;
        l8[i] = m;
        g8[i] = m;
    }
    __syncthreads();

    float* g9 = ws + mip_off(9);
    for (int i = tid; i < 18; i += 256) {
        int c = i % 3, f = i / 3;
        float m = (l8[f * 12 + c] + l8[f * 12 + 3 + c] +
                   l8[f * 12 + 6 + c] + l8[f * 12 + 9 + c]) * 0.25f;
        g9[i] = m;
    }
}

// ---------------------------------------------------------------------------
// Sampler
// ---------------------------------------------------------------------------
__device__ __forceinline__ const float* mip_base(const float* __restrict__ bg,
                                                 const float* __restrict__ ws,
                                                 int m) {
    if (m == 0) return bg;
    return ws + mip_off(m);
}

__device__ __forceinline__ void sample_mip(const float* __restrict__ tex, int Rm,
                                           int face, float s, float t,
                                           float out3[3]) {
    float u = s * (float)Rm - 0.5f;
    float v = t * (float)Rm - 0.5f;
    float u0 = floorf(u);
    float v0 = floorf(v);
    float fu = u - u0;
    float fv = v - v0;
    int u0i = min(max((int)u0, 0), Rm - 1);
    int u1i = min(max((int)u0 + 1, 0), Rm - 1);
    int v0i = min(max((int)v0, 0), Rm - 1);
    int v1i = min(max((int)v0 + 1, 0), Rm - 1);
    const float* r0 = tex + ((size_t)(face * Rm + v0i) * Rm) * 3;
    const float* r1 = tex + ((size_t)(face * Rm + v1i) * Rm) * 3;
    const float* p00 = r0 + (size_t)u0i * 3;
    const float* p01 = r0 + (size_t)u1i * 3;
    const float* p10 = r1 + (size_t)u0i * 3;
    const float* p11 = r1 + (size_t)u1i * 3;
#pragma unroll
    for (int c = 0; c < 3; ++c) {
        float top = p00[c] * (1.0f - fu) + p01[c] * fu;
        float bot = p10[c] * (1.0f - fu) + p11[c] * fu;
        out3[c] = top * (1.0f - fv) + bot * fv;
    }
}

__global__ __launch_bounds__(256) void cubemap_sample_kernel(
    const float* __restrict__ vd, const float* __restrict__ sa,
    const float* __restrict__ bg, const float* __restrict__ ws,
    float* __restrict__ out, int B,
    const float* __restrict__ p_brightness,
    const float* __restrict__ p_mul,
    const float* __restrict__ p_mipbias) {
    int i = blockIdx.x * blockDim.x + threadIdx.x;
    if (i >= B) return;

    float x = vd[3 * i + 0];
    float y = vd[3 * i + 1];
    float z = vd[3 * i + 2];
    float ax = fabsf(x), ay = fabsf(y), az = fabsf(z);
    float ma = fmaxf(ax, fmaxf(ay, az));

    int face;
    float sc, tc;
    if (ax >= ay && ax >= az) {
        face = (x > 0.0f) ? 0 : 1;
        sc = (x > 0.0f) ? -z : z;
        tc = -y;
    } else if (ay >= az) {
        face = (y > 0.0f) ? 2 : 3;
        sc = x;
        tc = (y > 0.0f) ? z : -z;
    } else {
        face = (z > 0.0f) ? 4 : 5;
        sc = (z > 0.0f) ? x : -x;
        tc = -y;
    }
    float s = 0.5f * (sc / ma + 1.0f);
    float t = 0.5f * (tc / ma + 1.0f);

    // mip = (saSample - log(clip(saTexel, EPS))) / log(4) / 2 + mipbias
    float distortion = 1.0f / ma;
    float saTexel = distortion * (1.0f / 262144.0f);  // /512/512 (exact pow2)
    const float EPSF = 1.1920928955078125e-07f;       // np.finfo(f32).eps
    const float LOG4 = 1.3862943611198906f;
    float mip = (sa[i] - logf(fmaxf(saTexel, EPSF))) / LOG4 * 0.5f + p_mipbias[0];
    mip = fminf(fmaxf(mip, 0.0f), (float)(N_MIPS - 1));

    int m0 = (int)floorf(mip);
    int m1 = min(m0 + 1, N_MIPS - 1);
    float frac = mip - (float)m0;

    float lo[3], hi[3];
    sample_mip(mip_base(bg, ws, m0), BASE_R >> m0, face, s, t, lo);
    sample_mip(mip_base(bg, ws, m1), BASE_R >> m1, face, s, t, hi);

    float bb = fminf(fmaxf(p_brightness[0], -1.0f), 2.0f);
    float mulv = p_mul[0];
#pragma unroll
    for (int c = 0; c < 3; ++c) {
        float xv = bb + mulv * (lo[c] * (1.0f - frac) + hi[c] * frac);
        float e = expf(xv);
        out[3 * i + c] = fminf(fmaxf(e, 0.01f), 1000.0f);
    }
}

extern "C" void kernel_launch(void* const* d_in, const int* in_sizes, int n_in,
                              void* d_out, int out_size, void* d_ws, size_t ws_size,
                              hipStream_t stream) {
    const float* viewdirs = (const float*)d_in[0];
    const float* saSample = (const float*)d_in[1];
    const float* bg_mat = (const float*)d_in[2];
    const float* brightness = (const float*)d_in[3];
    const float* mul = (const float*)d_in[4];
    const float* mipbias = (const float*)d_in[5];
    float* out = (float*)d_out;
    float* ws = (float*)d_ws;

    int B = in_sizes[1];  // saSample has B elements

    pyramid_fused_kernel<<<6 * 8 * 8, 256, 0, stream>>>(bg_mat, ws);
    pyramid_tail_kernel<<<1, 256, 0, stream>>>(ws);

    int blocks = (B + 255) / 256;
    cubemap_sample_kernel<<<blocks, 256, 0, stream>>>(
        viewdirs, saSample, bg_mat, ws, out, B, brightness, mul, mipbias);
}

// Round 3
// 33.199 us; speedup vs baseline: 1.3118x; 1.0205x over previous
//
#include <hip/hip_runtime.h>
#include <math.h>

// ---------------------------------------------------------------------------
// HierarchicalCubeMap: mip pyramid build (2 kernels, RGBA-padded levels 1..9)
// + per-ray trilinear cubemap sampling (1 kernel, float4 gathers).
// Inputs (f32): viewdirs (B,3), saSample (B,1), bg_mat (6,512,512,3),
//               brightness (1), mul (1), mipbias (1)
// Output (f32): (B,3) = clip(exp(clip(brightness,-1,2) + mul*sample), .01, 1000)
// ---------------------------------------------------------------------------

#define BASE_R 512
#define N_MIPS 10  // log2(512)+1

// float offset of RGBA-padded mip level m (m>=1) in workspace:
// level k holds 6*4*(512>>k)^2 floats; off4(m) = 8*(4^9 - 4^(10-m))
__device__ __forceinline__ size_t mip_off4(int m) {
    return (size_t)8 * (262144u - (1u << (2 * (10 - m))));
}

// ---------------------------------------------------------------------------
// Fused pyramid: levels 1..6. Grid = 6 faces * 8*8 tiles of 64x64 texels.
// LDS compute buffers are 3-stride; global pyramid is RGBA float4.
// Summation order matches chained 2x2 downsample: (a+b+c+d)*0.25.
// ---------------------------------------------------------------------------
__global__ __launch_bounds__(256) void pyramid_fused_kernel(
    const float* __restrict__ bg, float* __restrict__ ws) {
    __shared__ float bufA[64 * 64 * 3];  // 49152 B
    __shared__ float bufB[32 * 32 * 3];  // 12288 B

    const int tid = threadIdx.x;
    const int blk = blockIdx.x;
    const int tileX = blk & 7;
    const int tileY = (blk >> 3) & 7;
    const int f = blk >> 6;

    // Load 64 rows x 192 contiguous floats (=48 float4) per row.
    const size_t faceBase = (size_t)f * (512 * 512 * 3);
    for (int i = tid; i < 64 * 48; i += 256) {
        int row = i / 48;
        int col4 = i % 48;
        const float4 v = *reinterpret_cast<const float4*>(
            bg + faceBase + (size_t)(tileY * 64 + row) * 1536 + tileX * 192 + col4 * 4);
        *reinterpret_cast<float4*>(&bufA[row * 192 + col4 * 4]) = v;
    }
    __syncthreads();

    float* src = bufA;
    float* dst = bufB;
    int rs = 64;  // source tile dim
#pragma unroll
    for (int L = 1; L <= 6; ++L) {
        const int rd = rs >> 1;            // dest tile dim
        const int r = BASE_R >> L;         // dest level resolution
        float4* gl4 = reinterpret_cast<float4*>(ws + mip_off4(L)) + (size_t)f * r * r;
        const int y0 = tileY * rd;
        const int x0 = tileX * rd;
        const int n = rd * rd;
        for (int i = tid; i < n; i += 256) {
            int x = i % rd;
            int y = i / rd;
            const float* p0 = src + ((2 * y) * rs + 2 * x) * 3;
            const float* p1 = p0 + rs * 3;
            float m0 = (p0[0] + p0[3] + p1[0] + p1[3]) * 0.25f;
            float m1 = (p0[1] + p0[4] + p1[1] + p1[4]) * 0.25f;
            float m2 = (p0[2] + p0[5] + p1[2] + p1[5]) * 0.25f;
            dst[i * 3 + 0] = m0;
            dst[i * 3 + 1] = m1;
            dst[i * 3 + 2] = m2;
            gl4[(size_t)(y0 + y) * r + (x0 + x)] = make_float4(m0, m1, m2, 0.0f);
        }
        __syncthreads();
        float* tmp = src; src = dst; dst = tmp;
        rs = rd;
    }
}

// ---------------------------------------------------------------------------
// Tail: levels 7..9 from level 6 (6x8x8 texels). One block. RGBA in/out.
// ---------------------------------------------------------------------------
__global__ __launch_bounds__(256) void pyramid_tail_kernel(float* __restrict__ ws) {
    __shared__ float l6[1152];  // 6*8*8*3
    __shared__ float l7[288];   // 6*4*4*3
    __shared__ float l8[72];    // 6*2*2*3
    const int tid = threadIdx.x;

    const float4* g6 = reinterpret_cast<const float4*>(ws + mip_off4(6));
    for (int i = tid; i < 384; i += 256) {
        float4 v = g6[i];
        l6[i * 3 + 0] = v.x; l6[i * 3 + 1] = v.y; l6[i * 3 + 2] = v.z;
    }
    __syncthreads();

    float4* g7 = reinterpret_cast<float4*>(ws + mip_off4(7));
    for (int i = tid; i < 96; i += 256) {  // 6*4*4 texels
        int x = i % 4, y = (i / 4) % 4, f = i / 16;
        const float* p0 = l6 + ((f * 8 + 2 * y) * 8 + 2 * x) * 3;
        const float* p1 = p0 + 24;
        float m0 = (p0[0] + p0[3] + p1[0] + p1[3]) * 0.25f;
        float m1 = (p0[1] + p0[4] + p1[1] + p1[4]) * 0.25f;
        float m2 = (p0[2] + p0[5] + p1[2] + p1[5]) * 0.25f;
        l7[i * 3 + 0] = m0; l7[i * 3 + 1] = m1; l7[i * 3 + 2] = m2;
        g7[i] = make_float4(m0, m1, m2, 0.0f);
    }
    __syncthreads();

    float4* g8 = reinterpret_cast<float4*>(ws + mip_off4(8));
    for (int i = tid; i < 24; i += 256) {  // 6*2*2 texels
        int x = i % 2, y = (i / 2) % 2, f = i / 4;
        const float* p0 = l7 + ((f * 4 + 2 * y) * 4 + 2 * x) * 3;
        const float* p1 = p0 + 12;
        float m0 = (p0[0] + p0[3] + p1[0] + p1[3]) * 0.25f;
        float m1 = (p0[1] + p0[4] + p1[1] + p1[4]) * 0.25f;
        float m2 = (p0[2] + p0[5] + p1[2] + p1[5]) * 0.25f;
        l8[i * 3 + 0] = m0; l8[i * 3 + 1] = m1; l8[i * 3 + 2] = m2;
        g8[i] = make_float4(m0, m1, m2, 0.0f);
    }
    __syncthreads();

    float4* g9 = reinterpret_cast<float4*>(ws + mip_off4(9));
    for (int i = tid; i < 6; i += 256) {
        const float* p = l8 + i * 12;
        float m0 = (p[0] + p[3] + p[6] + p[9]) * 0.25f;
        float m1 = (p[1] + p[4] + p[7] + p[10]) * 0.25f;
        float m2 = (p[2] + p[5] + p[8] + p[11]) * 0.25f;
        g9[i] = make_float4(m0, m1, m2, 0.0f);
    }
}

// ---------------------------------------------------------------------------
// Sampler
// ---------------------------------------------------------------------------
__device__ __forceinline__ void corner_idx(int Rm, int face, float s, float t,
                                           int& i00, int& i01, int& i10, int& i11,
                                           float& fu, float& fv) {
    float u = s * (float)Rm - 0.5f;
    float v = t * (float)Rm - 0.5f;
    float u0 = floorf(u);
    float v0 = floorf(v);
    fu = u - u0;
    fv = v - v0;
    int u0i = min(max((int)u0, 0), Rm - 1);
    int u1i = min(max((int)u0 + 1, 0), Rm - 1);
    int v0i = min(max((int)v0, 0), Rm - 1);
    int v1i = min(max((int)v0 + 1, 0), Rm - 1);
    int fb = face * Rm;
    i00 = (fb + v0i) * Rm + u0i;
    i01 = (fb + v0i) * Rm + u1i;
    i10 = (fb + v1i) * Rm + u0i;
    i11 = (fb + v1i) * Rm + u1i;
}

__device__ __forceinline__ void blend4(float4 c00, float4 c01, float4 c10, float4 c11,
                                       float fu, float fv, float o[3]) {
    o[0] = (c00.x * (1.0f - fu) + c01.x * fu) * (1.0f - fv) +
           (c10.x * (1.0f - fu) + c11.x * fu) * fv;
    o[1] = (c00.y * (1.0f - fu) + c01.y * fu) * (1.0f - fv) +
           (c10.y * (1.0f - fu) + c11.y * fu) * fv;
    o[2] = (c00.z * (1.0f - fu) + c01.z * fu) * (1.0f - fv) +
           (c10.z * (1.0f - fu) + c11.z * fu) * fv;
}

// 3-stride fallback for mip 0 (bg_mat) — essentially never taken but required.
__device__ __noinline__ void sample_bg(const float* __restrict__ bg, int face,
                                       float s, float t, float o[3]) {
    const int Rm = BASE_R;
    int i00, i01, i10, i11;
    float fu, fv;
    corner_idx(Rm, face, s, t, i00, i01, i10, i11, fu, fv);
    const float* p00 = bg + (size_t)i00 * 3;
    const float* p01 = bg + (size_t)i01 * 3;
    const float* p10 = bg + (size_t)i10 * 3;
    const float* p11 = bg + (size_t)i11 * 3;
#pragma unroll
    for (int c = 0; c < 3; ++c) {
        float top = p00[c] * (1.0f - fu) + p01[c] * fu;
        float bot = p10[c] * (1.0f - fu) + p11[c] * fu;
        o[c] = top * (1.0f - fv) + bot * fv;
    }
}

__global__ __launch_bounds__(256) void cubemap_sample_kernel(
    const float* __restrict__ vd, const float* __restrict__ sa,
    const float* __restrict__ bg, const float* __restrict__ ws,
    float* __restrict__ out, int B,
    const float* __restrict__ p_brightness,
    const float* __restrict__ p_mul,
    const float* __restrict__ p_mipbias) {
    int i = blockIdx.x * blockDim.x + threadIdx.x;
    if (i >= B) return;

    float x = vd[3 * i + 0];
    float y = vd[3 * i + 1];
    float z = vd[3 * i + 2];
    float ax = fabsf(x), ay = fabsf(y), az = fabsf(z);
    float ma = fmaxf(ax, fmaxf(ay, az));

    int face;
    float sc, tc;
    if (ax >= ay && ax >= az) {
        face = (x > 0.0f) ? 0 : 1;
        sc = (x > 0.0f) ? -z : z;
        tc = -y;
    } else if (ay >= az) {
        face = (y > 0.0f) ? 2 : 3;
        sc = x;
        tc = (y > 0.0f) ? z : -z;
    } else {
        face = (z > 0.0f) ? 4 : 5;
        sc = (z > 0.0f) ? x : -x;
        tc = -y;
    }
    float s = 0.5f * (sc / ma + 1.0f);
    float t = 0.5f * (tc / ma + 1.0f);

    // mip = (saSample - log(clip(saTexel, EPS))) / log(4) / 2 + mipbias
    float distortion = 1.0f / ma;
    float saTexel = distortion * (1.0f / 262144.0f);  // /512/512 (exact pow2)
    const float EPSF = 1.1920928955078125e-07f;       // np.finfo(f32).eps
    const float LOG4 = 1.3862943611198906f;
    float mip = (sa[i] - logf(fmaxf(saTexel, EPSF))) / LOG4 * 0.5f + p_mipbias[0];
    mip = fminf(fmaxf(mip, 0.0f), (float)(N_MIPS - 1));

    int m0 = (int)floorf(mip);
    int m1 = min(m0 + 1, N_MIPS - 1);
    float frac = mip - (float)m0;

    float lo[3], hi[3];
    if (m0 >= 1) {
        // Hot path: both mips RGBA in ws. Compute all addresses, then issue
        // all 8 dwordx4 gathers, then blend (max ILP).
        const float4* ta = reinterpret_cast<const float4*>(ws + mip_off4(m0));
        const float4* tb = reinterpret_cast<const float4*>(ws + mip_off4(m1));
        int Ra = BASE_R >> m0, Rb = BASE_R >> m1;
        int a00, a01, a10, a11, b00, b01, b10, b11;
        float afu, afv, bfu, bfv;
        corner_idx(Ra, face, s, t, a00, a01, a10, a11, afu, afv);
        corner_idx(Rb, face, s, t, b00, b01, b10, b11, bfu, bfv);
        float4 A00 = ta[a00], A01 = ta[a01], A10 = ta[a10], A11 = ta[a11];
        float4 B00 = tb[b00], B01 = tb[b01], B10 = tb[b10], B11 = tb[b11];
        blend4(A00, A01, A10, A11, afu, afv, lo);
        blend4(B00, B01, B10, B11, bfu, bfv, hi);
    } else {
        // m0 == 0: lo from bg (3-stride); m1 == 1 -> hi from ws.
        sample_bg(bg, face, s, t, lo);
        const float4* tb = reinterpret_cast<const float4*>(ws + mip_off4(1));
        int Rb = BASE_R >> 1;
        int b00, b01, b10, b11;
        float bfu, bfv;
        corner_idx(Rb, face, s, t, b00, b01, b10, b11, bfu, bfv);
        blend4(tb[b00], tb[b01], tb[b10], tb[b11], bfu, bfv, hi);
    }

    float bb = fminf(fmaxf(p_brightness[0], -1.0f), 2.0f);
    float mulv = p_mul[0];
#pragma unroll
    for (int c = 0; c < 3; ++c) {
        float xv = bb + mulv * (lo[c] * (1.0f - frac) + hi[c] * frac);
        float e = expf(xv);
        out[3 * i + c] = fminf(fmaxf(e, 0.01f), 1000.0f);
    }
}

extern "C" void kernel_launch(void* const* d_in, const int* in_sizes, int n_in,
                              void* d_out, int out_size, void* d_ws, size_t ws_size,
                              hipStream_t stream) {
    const float* viewdirs = (const float*)d_in[0];
    const float* saSample = (const float*)d_in[1];
    const float* bg_mat = (const float*)d_in[2];
    const float* brightness = (const float*)d_in[3];
    const float* mul = (const float*)d_in[4];
    const float* mipbias = (const float*)d_in[5];
    float* out = (float*)d_out;
    float* ws = (float*)d_ws;

    int B = in_sizes[1];  // saSample has B elements

    pyramid_fused_kernel<<<6 * 8 * 8, 256, 0, stream>>>(bg_mat, ws);
    pyramid_tail_kernel<<<1, 256, 0, stream>>>(ws);

    int blocks = (B + 255) / 256;
    cubemap_sample_kernel<<<blocks, 256, 0, stream>>>(
        viewdirs, saSample, bg_mat, ws, out, B, brightness, mul, mipbias);
}

// Round 4
// 32.403 us; speedup vs baseline: 1.3441x; 1.0246x over previous
//
#include <hip/hip_runtime.h>
#include <math.h>

// ---------------------------------------------------------------------------
// HierarchicalCubeMap: mip pyramid build (2 kernels, RGBA-padded levels 1..9)
// + per-ray trilinear cubemap sampling (1 kernel, float4 gathers).
// Inputs (f32): viewdirs (B,3), saSample (B,1), bg_mat (6,512,512,3),
//               brightness (1), mul (1), mipbias (1)
// Output (f32): (B,3) = clip(exp(clip(brightness,-1,2) + mul*sample), .01, 1000)
// ---------------------------------------------------------------------------

#define BASE_R 512
#define N_MIPS 10  // log2(512)+1

// float offset of RGBA-padded mip level m (m>=1) in workspace:
// level k holds 6*4*(512>>k)^2 floats; off4(m) = 8*(4^9 - 4^(10-m))
__device__ __forceinline__ size_t mip_off4(int m) {
    return (size_t)8 * (262144u - (1u << (2 * (10 - m))));
}

// ---------------------------------------------------------------------------
// Fused pyramid: levels 1..5. Grid = 6 faces * 16*16 tiles of 32x32 texels.
// 15 KB LDS/block -> 8 blocks/CU cap; 1536 blocks all co-resident.
// Summation order matches chained 2x2 downsample: (a+b+c+d)*0.25.
// ---------------------------------------------------------------------------
__global__ __launch_bounds__(256) void pyramid_fused_kernel(
    const float* __restrict__ bg, float* __restrict__ ws) {
    __shared__ float bufA[32 * 32 * 3];  // 12288 B
    __shared__ float bufB[16 * 16 * 3];  //  3072 B

    const int tid = threadIdx.x;
    const int blk = blockIdx.x;
    const int tileX = blk & 15;
    const int tileY = (blk >> 4) & 15;
    const int f = blk >> 8;

    // Load 32 rows x 96 contiguous floats (=24 float4) per row; 3 f4/thread.
    const size_t faceBase = (size_t)f * (512 * 512 * 3);
    for (int i = tid; i < 32 * 24; i += 256) {
        int row = i / 24;
        int col4 = i % 24;
        const float4 v = *reinterpret_cast<const float4*>(
            bg + faceBase + (size_t)(tileY * 32 + row) * 1536 + tileX * 96 + col4 * 4);
        *reinterpret_cast<float4*>(&bufA[row * 96 + col4 * 4]) = v;
    }
    __syncthreads();

    float* src = bufA;
    float* dst = bufB;
    int rs = 32;  // source tile dim
#pragma unroll
    for (int L = 1; L <= 5; ++L) {
        const int rd = rs >> 1;            // dest tile dim (16,8,4,2,1)
        const int r = BASE_R >> L;         // dest level resolution
        float4* gl4 = reinterpret_cast<float4*>(ws + mip_off4(L)) + (size_t)f * r * r;
        const int y0 = tileY * rd;
        const int x0 = tileX * rd;
        const int n = rd * rd;
        for (int i = tid; i < n; i += 256) {
            int x = i % rd;
            int y = i / rd;
            const float* p0 = src + ((2 * y) * rs + 2 * x) * 3;
            const float* p1 = p0 + rs * 3;
            float m0 = (p0[0] + p0[3] + p1[0] + p1[3]) * 0.25f;
            float m1 = (p0[1] + p0[4] + p1[1] + p1[4]) * 0.25f;
            float m2 = (p0[2] + p0[5] + p1[2] + p1[5]) * 0.25f;
            dst[i * 3 + 0] = m0;
            dst[i * 3 + 1] = m1;
            dst[i * 3 + 2] = m2;
            gl4[(size_t)(y0 + y) * r + (x0 + x)] = make_float4(m0, m1, m2, 0.0f);
        }
        __syncthreads();
        float* tmp = src; src = dst; dst = tmp;
        rs = rd;
    }
}

// ---------------------------------------------------------------------------
// Tail: levels 6..9 from level 5 (6x16x16 texels, 24 KB). One block.
// ---------------------------------------------------------------------------
__global__ __launch_bounds__(256) void pyramid_tail_kernel(float* __restrict__ ws) {
    __shared__ float l5[4608];  // 6*16*16*3
    __shared__ float l6[1152];  // 6*8*8*3
    __shared__ float l7[288];   // 6*4*4*3
    __shared__ float l8[72];    // 6*2*2*3
    const int tid = threadIdx.x;

    const float4* g5 = reinterpret_cast<const float4*>(ws + mip_off4(5));
    for (int i = tid; i < 1536; i += 256) {
        float4 v = g5[i];
        l5[i * 3 + 0] = v.x; l5[i * 3 + 1] = v.y; l5[i * 3 + 2] = v.z;
    }
    __syncthreads();

    float4* g6 = reinterpret_cast<float4*>(ws + mip_off4(6));
    for (int i = tid; i < 384; i += 256) {  // 6*8*8 texels
        int x = i & 7, y = (i >> 3) & 7, f = i >> 6;
        const float* p0 = l5 + ((f * 16 + 2 * y) * 16 + 2 * x) * 3;
        const float* p1 = p0 + 48;
        float m0 = (p0[0] + p0[3] + p1[0] + p1[3]) * 0.25f;
        float m1 = (p0[1] + p0[4] + p1[1] + p1[4]) * 0.25f;
        float m2 = (p0[2] + p0[5] + p1[2] + p1[5]) * 0.25f;
        l6[i * 3 + 0] = m0; l6[i * 3 + 1] = m1; l6[i * 3 + 2] = m2;
        g6[i] = make_float4(m0, m1, m2, 0.0f);
    }
    __syncthreads();

    float4* g7 = reinterpret_cast<float4*>(ws + mip_off4(7));
    for (int i = tid; i < 96; i += 256) {  // 6*4*4 texels
        int x = i & 3, y = (i >> 2) & 3, f = i >> 4;
        const float* p0 = l6 + ((f * 8 + 2 * y) * 8 + 2 * x) * 3;
        const float* p1 = p0 + 24;
        float m0 = (p0[0] + p0[3] + p1[0] + p1[3]) * 0.25f;
        float m1 = (p0[1] + p0[4] + p1[1] + p1[4]) * 0.25f;
        float m2 = (p0[2] + p0[5] + p1[2] + p1[5]) * 0.25f;
        l7[i * 3 + 0] = m0; l7[i * 3 + 1] = m1; l7[i * 3 + 2] = m2;
        g7[i] = make_float4(m0, m1, m2, 0.0f);
    }
    __syncthreads();

    float4* g8 = reinterpret_cast<float4*>(ws + mip_off4(8));
    for (int i = tid; i < 24; i += 256) {  // 6*2*2 texels
        int x = i & 1, y = (i >> 1) & 1, f = i >> 2;
        const float* p0 = l7 + ((f * 4 + 2 * y) * 4 + 2 * x) * 3;
        const float* p1 = p0 + 12;
        float m0 = (p0[0] + p0[3] + p1[0] + p1[3]) * 0.25f;
        float m1 = (p0[1] + p0[4] + p1[1] + p1[4]) * 0.25f;
        float m2 = (p0[2] + p0[5] + p1[2] + p1[5]) * 0.25f;
        l8[i * 3 + 0] = m0; l8[i * 3 + 1] = m1; l8[i * 3 + 2] = m2;
        g8[i] = make_float4(m0, m1, m2, 0.0f);
    }
    __syncthreads();

    float4* g9 = reinterpret_cast<float4*>(ws + mip_off4(9));
    for (int i = tid; i < 6; i += 256) {
        const float* p = l8 + i * 12;
        float m0 = (p[0] + p[3] + p[6] + p[9]) * 0.25f;
        float m1 = (p[1] + p[4] + p[7] + p[10]) * 0.25f;
        float m2 = (p[2] + p[5] + p[8] + p[11]) * 0.25f;
        g9[i] = make_float4(m0, m1, m2, 0.0f);
    }
}

// ---------------------------------------------------------------------------
// Sampler (unchanged from round 3)
// ---------------------------------------------------------------------------
__device__ __forceinline__ void corner_idx(int Rm, int face, float s, float t,
                                           int& i00, int& i01, int& i10, int& i11,
                                           float& fu, float& fv) {
    float u = s * (float)Rm - 0.5f;
    float v = t * (float)Rm - 0.5f;
    float u0 = floorf(u);
    float v0 = floorf(v);
    fu = u - u0;
    fv = v - v0;
    int u0i = min(max((int)u0, 0), Rm - 1);
    int u1i = min(max((int)u0 + 1, 0), Rm - 1);
    int v0i = min(max((int)v0, 0), Rm - 1);
    int v1i = min(max((int)v0 + 1, 0), Rm - 1);
    int fb = face * Rm;
    i00 = (fb + v0i) * Rm + u0i;
    i01 = (fb + v0i) * Rm + u1i;
    i10 = (fb + v1i) * Rm + u0i;
    i11 = (fb + v1i) * Rm + u1i;
}

__device__ __forceinline__ void blend4(float4 c00, float4 c01, float4 c10, float4 c11,
                                       float fu, float fv, float o[3]) {
    o[0] = (c00.x * (1.0f - fu) + c01.x * fu) * (1.0f - fv) +
           (c10.x * (1.0f - fu) + c11.x * fu) * fv;
    o[1] = (c00.y * (1.0f - fu) + c01.y * fu) * (1.0f - fv) +
           (c10.y * (1.0f - fu) + c11.y * fu) * fv;
    o[2] = (c00.z * (1.0f - fu) + c01.z * fu) * (1.0f - fv) +
           (c10.z * (1.0f - fu) + c11.z * fu) * fv;
}

// 3-stride fallback for mip 0 (bg_mat) — essentially never taken but required.
__device__ __noinline__ void sample_bg(const float* __restrict__ bg, int face,
                                       float s, float t, float o[3]) {
    const int Rm = BASE_R;
    int i00, i01, i10, i11;
    float fu, fv;
    corner_idx(Rm, face, s, t, i00, i01, i10, i11, fu, fv);
    const float* p00 = bg + (size_t)i00 * 3;
    const float* p01 = bg + (size_t)i01 * 3;
    const float* p10 = bg + (size_t)i10 * 3;
    const float* p11 = bg + (size_t)i11 * 3;
#pragma unroll
    for (int c = 0; c < 3; ++c) {
        float top = p00[c] * (1.0f - fu) + p01[c] * fu;
        float bot = p10[c] * (1.0f - fu) + p11[c] * fu;
        o[c] = top * (1.0f - fv) + bot * fv;
    }
}

__global__ __launch_bounds__(256) void cubemap_sample_kernel(
    const float* __restrict__ vd, const float* __restrict__ sa,
    const float* __restrict__ bg, const float* __restrict__ ws,
    float* __restrict__ out, int B,
    const float* __restrict__ p_brightness,
    const float* __restrict__ p_mul,
    const float* __restrict__ p_mipbias) {
    int i = blockIdx.x * blockDim.x + threadIdx.x;
    if (i >= B) return;

    float x = vd[3 * i + 0];
    float y = vd[3 * i + 1];
    float z = vd[3 * i + 2];
    float ax = fabsf(x), ay = fabsf(y), az = fabsf(z);
    float ma = fmaxf(ax, fmaxf(ay, az));

    int face;
    float sc, tc;
    if (ax >= ay && ax >= az) {
        face = (x > 0.0f) ? 0 : 1;
        sc = (x > 0.0f) ? -z : z;
        tc = -y;
    } else if (ay >= az) {
        face = (y > 0.0f) ? 2 : 3;
        sc = x;
        tc = (y > 0.0f) ? z : -z;
    } else {
        face = (z > 0.0f) ? 4 : 5;
        sc = (z > 0.0f) ? x : -x;
        tc = -y;
    }
    float s = 0.5f * (sc / ma + 1.0f);
    float t = 0.5f * (tc / ma + 1.0f);

    // mip = (saSample - log(clip(saTexel, EPS))) / log(4) / 2 + mipbias
    float distortion = 1.0f / ma;
    float saTexel = distortion * (1.0f / 262144.0f);  // /512/512 (exact pow2)
    const float EPSF = 1.1920928955078125e-07f;       // np.finfo(f32).eps
    const float LOG4 = 1.3862943611198906f;
    float mip = (sa[i] - logf(fmaxf(saTexel, EPSF))) / LOG4 * 0.5f + p_mipbias[0];
    mip = fminf(fmaxf(mip, 0.0f), (float)(N_MIPS - 1));

    int m0 = (int)floorf(mip);
    int m1 = min(m0 + 1, N_MIPS - 1);
    float frac = mip - (float)m0;

    float lo[3], hi[3];
    if (m0 >= 1) {
        const float4* ta = reinterpret_cast<const float4*>(ws + mip_off4(m0));
        const float4* tb = reinterpret_cast<const float4*>(ws + mip_off4(m1));
        int Ra = BASE_R >> m0, Rb = BASE_R >> m1;
        int a00, a01, a10, a11, b00, b01, b10, b11;
        float afu, afv, bfu, bfv;
        corner_idx(Ra, face, s, t, a00, a01, a10, a11, afu, afv);
        corner_idx(Rb, face, s, t, b00, b01, b10, b11, bfu, bfv);
        float4 A00 = ta[a00], A01 = ta[a01], A10 = ta[a10], A11 = ta[a11];
        float4 B00 = tb[b00], B01 = tb[b01], B10 = tb[b10], B11 = tb[b11];
        blend4(A00, A01, A10, A11, afu, afv, lo);
        blend4(B00, B01, B10, B11, bfu, bfv, hi);
    } else {
        sample_bg(bg, face, s, t, lo);
        const float4* tb = reinterpret_cast<const float4*>(ws + mip_off4(1));
        int Rb = BASE_R >> 1;
        int b00, b01, b10, b11;
        float bfu, bfv;
        corner_idx(Rb, face, s, t, b00, b01, b10, b11, bfu, bfv);
        blend4(tb[b00], tb[b01], tb[b10], tb[b11], bfu, bfv, hi);
    }

    float bb = fminf(fmaxf(p_brightness[0], -1.0f), 2.0f);
    float mulv = p_mul[0];
#pragma unroll
    for (int c = 0; c < 3; ++c) {
        float xv = bb + mulv * (lo[c] * (1.0f - frac) + hi[c] * frac);
        float e = expf(xv);
        out[3 * i + c] = fminf(fmaxf(e, 0.01f), 1000.0f);
    }
}

extern "C" void kernel_launch(void* const* d_in, const int* in_sizes, int n_in,
                              void* d_out, int out_size, void* d_ws, size_t ws_size,
                              hipStream_t stream) {
    const float* viewdirs = (const float*)d_in[0];
    const float* saSample = (const float*)d_in[1];
    const float* bg_mat = (const float*)d_in[2];
    const float* brightness = (const float*)d_in[3];
    const float* mul = (const float*)d_in[4];
    const float* mipbias = (const float*)d_in[5];
    float* out = (float*)d_out;
    float* ws = (float*)d_ws;

    int B = in_sizes[1];  // saSample has B elements

    pyramid_fused_kernel<<<6 * 16 * 16, 256, 0, stream>>>(bg_mat, ws);
    pyramid_tail_kernel<<<1, 256, 0, stream>>>(ws);

    int blocks = (B + 255) / 256;
    cubemap_sample_kernel<<<blocks, 256, 0, stream>>>(
        viewdirs, saSample, bg_mat, ws, out, B, brightness, mul, mipbias);
}